// Round 13
// baseline (714.238 us; speedup 1.0000x reference)
//
#include <hip/hip_runtime.h>
#include <hip/hip_bf16.h>

#define NN_NODES 100000
#define NE_EDGES 1000000
#define D_IN 512
#define D_H0 512
#define D_H1 256
#define D_C  64

using f32x4  = __attribute__((ext_vector_type(4))) float;
using h16x8  = __attribute__((ext_vector_type(8))) _Float16;

// ---------------- fp32 row-major -> fp16 TILED [(R/128)][(K/32)][128x32] ----------------
__global__ __launch_bounds__(256) void tof16_tiled_kernel(
    const float* __restrict__ w, _Float16* __restrict__ o, int R, int K)
{
    int i = blockIdx.x * 256 + threadIdx.x;      // 8 elems along a row
    int n8 = R * (K >> 3);
    if (i >= n8) return;
    int kd = K >> 3;
    int r  = i / kd;
    int c0 = (i - r * kd) * 8;
    const f32x4 a = *(const f32x4*)(w + (size_t)r * K + c0);
    const f32x4 b = *(const f32x4*)(w + (size_t)r * K + c0 + 4);
    h16x8 h;
    #pragma unroll
    for (int j = 0; j < 4; j++){
        h[j]   = (_Float16)a[j];
        h[j+4] = (_Float16)b[j];
    }
    size_t off = ((size_t)(r >> 7) * (K >> 5) + (c0 >> 5)) * 4096
               + (size_t)(r & 127) * 32 + (c0 & 31);
    *(h16x8*)(o + off) = h;
}

// ---------------- GEMM: C[M,NNc] = act( A[M,K] * B[NNc,K]^T + bias ) ----------------
// ZERO-LDS, ZERO-BARRIER register GEMM over TILED operands.
// Tiled layout makes every fragment load a contiguous 1KB burst per wave
// (the property whose absence killed the row-major register GEMM of r7):
//   af[mf]: rows wm*64+mf*16+fr, cols fc*8 of a [128][32] slab -> 1KB linear.
// A rows are wave-exclusive; B rows shared by 2 waves (L1/L2 serve repeats).
// Register double-buffer, K fully unrolled, compiler-inserted counted vmcnt;
// waves self-pace (no __syncthreads anywhere). acc 32 + bufs 48 + addr < 128
// regs -> 4 waves/SIMD. setprio around MFMA clusters.
// OMODE: 1 fp16 out TILED; 2 dual row-major fp16 out (O1=v, O2=v*scale[row]).
template<bool RELU, int OMODE, int BN_T, int NBN, int KK>
__global__ __launch_bounds__(256, 4) void gemm_kernel(
    const _Float16* __restrict__ A,
    const _Float16* __restrict__ B,
    const float* __restrict__ bias,
    void* __restrict__ O1, _Float16* __restrict__ O2, const float* __restrict__ scale,
    int M, int NNc, int xq, int xr)
{
    constexpr int NTK = KK / 32;           // k-steps (even, >= 8)
    constexpr int NF  = BN_T / 32;         // n-fragments per wave

    const int tid  = threadIdx.x;
    const int lane = tid & 63;
    const int wv   = tid >> 6;
    const int wm   = wv >> 1;
    const int wn   = wv & 1;
    const int fr   = lane & 15;
    const int fc   = lane >> 4;

    // bijective XCD-chunk swizzle (m204)
    const int bid = blockIdx.x;
    const int xcd = bid & 7;
    const int i8  = bid >> 3;
    const int L   = ((xcd < xr) ? xcd * (xq + 1) : xr * (xq + 1) + (xcd - xr) * xq) + i8;
    const int mt  = L / NBN;
    const int bn  = L - mt * NBN;
    const int bm0 = mt * 128;
    const int bn0 = bn * BN_T;

    // B rows live in 128-row slabs: locate tile within its slab
    const int bslab = bn0 >> 7;
    const int binsl = bn0 & 127;

    // per-lane fragment offsets within a slab (constant across k)
    int aoff[4], boff[NF];
    #pragma unroll
    for (int mf = 0; mf < 4; mf++)
        aoff[mf] = (wm * 64 + mf * 16 + fr) * 32 + fc * 8;
    #pragma unroll
    for (int nf = 0; nf < NF; nf++)
        boff[nf] = (binsl + wn * (BN_T / 2) + nf * 16 + fr) * 32 + fc * 8;

    const _Float16* Abase = A + (size_t)mt * NTK * 4096;
    const _Float16* Bbase = B + (size_t)bslab * NTK * 4096;

    f32x4 acc[4][NF] = {};
    h16x8 a0[4], a1[4], b0[NF], b1[NF];

    auto loadAB = [&](h16x8 (&af)[4], h16x8 (&bf)[NF], int t){
        const _Float16* as = Abase + t * 4096;
        const _Float16* bs = Bbase + t * 4096;
        #pragma unroll
        for (int mf = 0; mf < 4; mf++) af[mf] = *(const h16x8*)(as + aoff[mf]);
        #pragma unroll
        for (int nf = 0; nf < NF; nf++) bf[nf] = *(const h16x8*)(bs + boff[nf]);
    };

    auto mma = [&](h16x8 (&af)[4], h16x8 (&bf)[NF]){
        __builtin_amdgcn_s_setprio(1);
        #pragma unroll
        for (int mf = 0; mf < 4; mf++)
            #pragma unroll
            for (int nf = 0; nf < NF; nf++)
                acc[mf][nf] = __builtin_amdgcn_mfma_f32_16x16x32_f16(af[mf], bf[nf], acc[mf][nf], 0, 0, 0);
        __builtin_amdgcn_s_setprio(0);
    };

    loadAB(a0, b0, 0);
    #pragma unroll
    for (int t = 0; t < NTK - 2; t += 2){
        loadAB(a1, b1, t + 1);
        mma(a0, b0);
        loadAB(a0, b0, t + 2);
        mma(a1, b1);
    }
    loadAB(a1, b1, NTK - 1);
    mma(a0, b0);
    mma(a1, b1);

    // ---- epilogue ----
    #pragma unroll
    for (int mf = 0; mf < 4; mf++){
        #pragma unroll
        for (int nf = 0; nf < NF; nf++){
            #pragma unroll
            for (int r = 0; r < 4; r++){
                int rg = bm0 + wm * 64 + mf * 16 + fc * 4 + r;
                int cg = bn0 + wn * (BN_T / 2) + nf * 16 + fr;
                if (rg < M){
                    float v = acc[mf][nf][r] + bias[cg];
                    if constexpr (RELU) v = fmaxf(v, 0.f);
                    if constexpr (OMODE == 1){
                        size_t o = ((size_t)mt * (NNc >> 5) + (cg >> 5)) * 4096
                                 + (size_t)(rg & 127) * 32 + (cg & 31);
                        ((_Float16*)O1)[o] = (_Float16)v;
                    } else {
                        ((_Float16*)O1)[(size_t)rg * NNc + cg] = (_Float16)v;
                        O2[(size_t)rg * NNc + cg] = (_Float16)(v * scale[rg]);
                    }
                }
            }
        }
    }
}

// ---------------- graph preprocessing ----------------
__global__ void degrees_kernel(const int* __restrict__ src, const int* __restrict__ dst,
                               int* __restrict__ dout, int* __restrict__ din){
    int e = blockIdx.x * blockDim.x + threadIdx.x;
    if (e < NE_EDGES){
        atomicAdd(&dout[src[e]], 1);
        atomicAdd(&din[dst[e]], 1);
    }
}

__global__ void norm_kernel(const int* __restrict__ dout, const int* __restrict__ din,
                            float* __restrict__ ns, float* __restrict__ nd, int n){
    int i = blockIdx.x * blockDim.x + threadIdx.x;
    if (i < n){
        ns[i] = rsqrtf((float)(dout[i] > 1 ? dout[i] : 1));
        nd[i] = rsqrtf((float)(din[i]  > 1 ? din[i]  : 1));
    }
}

__global__ __launch_bounds__(256) void scan1_kernel(const int* __restrict__ din,
                                                    int* __restrict__ part,
                                                    int* __restrict__ bsum, int n){
    __shared__ int s[256];
    int i = blockIdx.x * 256 + threadIdx.x;
    int v = (i < n) ? din[i] : 0;
    s[threadIdx.x] = v;
    __syncthreads();
    for (int off = 1; off < 256; off <<= 1){
        int t = (threadIdx.x >= off) ? s[threadIdx.x - off] : 0;
        __syncthreads();
        s[threadIdx.x] += t;
        __syncthreads();
    }
    if (i < n) part[i] = s[threadIdx.x];
    if (threadIdx.x == 255) bsum[blockIdx.x] = s[255];
}

__global__ __launch_bounds__(512) void scan2_kernel(int* __restrict__ bsum, int nb){
    __shared__ int s[512];
    int v = (threadIdx.x < nb) ? bsum[threadIdx.x] : 0;
    s[threadIdx.x] = v;
    __syncthreads();
    for (int off = 1; off < 512; off <<= 1){
        int t = (threadIdx.x >= off) ? s[threadIdx.x - off] : 0;
        __syncthreads();
        s[threadIdx.x] += t;
        __syncthreads();
    }
    if (threadIdx.x < nb) bsum[threadIdx.x] = s[threadIdx.x];
}

__global__ void scan3_kernel(const int* __restrict__ part, const int* __restrict__ din,
                             const int* __restrict__ bsum, int* __restrict__ offs,
                             int* __restrict__ cur, int n){
    int i = blockIdx.x * 256 + threadIdx.x;
    if (i < n){
        int base = (blockIdx.x > 0) ? bsum[blockIdx.x - 1] : 0;
        int excl = base + part[i] - din[i];
        offs[i] = excl;
        cur[i]  = excl;
    }
}

__global__ void fill_kernel(const int* __restrict__ src, const int* __restrict__ dst,
                            int* __restrict__ cur, int* __restrict__ csr){
    int e = blockIdx.x * blockDim.x + threadIdx.x;
    if (e < NE_EDGES){
        int d = dst[e];
        int pos = atomicAdd(&cur[d], 1);
        csr[pos] = src[e];
    }
}

// ---------------- APPNP propagation v3.2: 8 lanes per node, 4-way unrolled ----------------
__global__ __launch_bounds__(256) void propagate_kernel(
    const _Float16* __restrict__ hs, const _Float16* __restrict__ h0h,
    float* __restrict__ hout, _Float16* __restrict__ houts,
    const int* __restrict__ offs, const int* __restrict__ din,
    const int* __restrict__ csr,
    const float* __restrict__ ns, const float* __restrict__ nd)
{
    int t    = blockIdx.x * 256 + threadIdx.x;
    int node = t >> 3;
    int gl   = t & 7;
    if (node >= NN_NODES) return;
    int start = offs[node];
    int deg   = din[node];
    float acc[8] = {};
    int j = 0;
    for (; j + 4 <= deg; j += 4){
        int s0 = csr[start + j];
        int s1 = csr[start + j + 1];
        int s2 = csr[start + j + 2];
        int s3 = csr[start + j + 3];
        h16x8 v0 = *(const h16x8*)(hs + (size_t)s0 * D_C + gl * 8);
        h16x8 v1 = *(const h16x8*)(hs + (size_t)s1 * D_C + gl * 8);
        h16x8 v2 = *(const h16x8*)(hs + (size_t)s2 * D_C + gl * 8);
        h16x8 v3 = *(const h16x8*)(hs + (size_t)s3 * D_C + gl * 8);
        #pragma unroll
        for (int i = 0; i < 8; i++)
            acc[i] += ((float)v0[i] + (float)v1[i]) + ((float)v2[i] + (float)v3[i]);
    }
    for (; j < deg; j++){
        int s0 = csr[start + j];
        h16x8 v0 = *(const h16x8*)(hs + (size_t)s0 * D_C + gl * 8);
        #pragma unroll
        for (int i = 0; i < 8; i++) acc[i] += (float)v0[i];
    }
    float ndv = 0.9f * nd[node];
    h16x8 h0v = *(const h16x8*)(h0h + (size_t)node * D_C + gl * 8);
    float out[8];
    #pragma unroll
    for (int i = 0; i < 8; i++) out[i] = acc[i] * ndv + 0.1f * (float)h0v[i];
    if (houts){
        float nsv = ns[node];
        h16x8 o;
        #pragma unroll
        for (int i = 0; i < 8; i++) o[i] = (_Float16)(out[i] * nsv);
        *(h16x8*)(houts + (size_t)node * D_C + gl * 8) = o;
    }
    if (hout){
        f32x4 oa, ob;
        #pragma unroll
        for (int i = 0; i < 4; i++){ oa[i] = out[i]; ob[i] = out[i + 4]; }
        *(f32x4*)(hout + (size_t)node * D_C + gl * 8)     = oa;
        *(f32x4*)(hout + (size_t)node * D_C + gl * 8 + 4) = ob;
    }
}

// ---------------- launch ----------------
extern "C" void kernel_launch(void* const* d_in, const int* in_sizes, int n_in,
                              void* d_out, int out_size, void* d_ws, size_t ws_size,
                              hipStream_t stream)
{
    const float* features = (const float*)d_in[0];
    const int*   edge     = (const int*)d_in[1];
    const float* W0 = (const float*)d_in[2];
    const float* b0 = (const float*)d_in[3];
    const float* W1 = (const float*)d_in[4];
    const float* b1 = (const float*)d_in[5];
    const float* W2 = (const float*)d_in[6];
    const float* b2 = (const float*)d_in[7];
    const int* src = edge;
    const int* dst = edge + NE_EDGES;

    char* p = (char*)d_ws;
    auto alloc = [&](size_t bytes) -> char* {
        char* r = p;
        p += (bytes + 255) & ~(size_t)255;
        return r;
    };

    const int MT = (NN_NODES + 127) / 128;              // 782 m-tiles
    const size_t FEAT_T = (size_t)MT * 16 * 4096 * 2;   // tiled fp16, K=512
    const size_t HBUFH  = (size_t)NN_NODES * D_C * 2;   // 12.8 MB fp16

    _Float16* w0f = (_Float16*)alloc((size_t)4 * 16 * 4096 * 2);  // 512 rows
    _Float16* w1f = (_Float16*)alloc((size_t)2 * 16 * 4096 * 2);  // 256 rows
    _Float16* w2f = (_Float16*)alloc((size_t)1 * 8  * 4096 * 2);  // 64 rows
    char* R1 = alloc(FEAT_T);          // fhf (tiled); later act2 (tiled)
    char* R2 = alloc(FEAT_T);          // act1 (tiled); later h0h + h0s + hAs + hBs
    int*   deg_out = (int*)alloc((size_t)NN_NODES * 4);
    int*   deg_in  = (int*)alloc((size_t)NN_NODES * 4);
    float* nsrc    = (float*)alloc((size_t)NN_NODES * 4);
    float* ndst    = (float*)alloc((size_t)NN_NODES * 4);
    int*   part    = (int*)alloc((size_t)NN_NODES * 4);
    int*   bsum    = (int*)alloc(2048);
    int*   offs    = (int*)alloc((size_t)NN_NODES * 4);
    int*   cur     = (int*)alloc((size_t)NN_NODES * 4);
    int*   csr     = (int*)alloc((size_t)NE_EDGES * 4);
    if ((size_t)(p - (char*)d_ws) > ws_size) return;

    _Float16* fhf  = (_Float16*)R1;          // dead after GEMM1
    _Float16* act2 = (_Float16*)R1;          // written by GEMM2 (tiled)
    _Float16* act1 = (_Float16*)R2;          // dead after GEMM2
    _Float16* h0h  = (_Float16*)R2;          // written by GEMM3 (row-major fp16)
    _Float16* h0s  = (_Float16*)(R2 + HBUFH);
    _Float16* hAs  = (_Float16*)(R2 + 2 * HBUFH);
    _Float16* hBs  = (_Float16*)(R2 + 3 * HBUFH);

    // --- graph preprocessing ---
    hipMemsetAsync(deg_out, 0, (size_t)NN_NODES * 4, stream);
    hipMemsetAsync(deg_in,  0, (size_t)NN_NODES * 4, stream);
    degrees_kernel<<<(NE_EDGES + 255) / 256, 256, 0, stream>>>(src, dst, deg_out, deg_in);
    norm_kernel<<<(NN_NODES + 255) / 256, 256, 0, stream>>>(deg_out, deg_in, nsrc, ndst, NN_NODES);
    int nb = (NN_NODES + 255) / 256;
    scan1_kernel<<<nb, 256, 0, stream>>>(deg_in, part, bsum, NN_NODES);
    scan2_kernel<<<1, 512, 0, stream>>>(bsum, nb);
    scan3_kernel<<<nb, 256, 0, stream>>>(part, deg_in, bsum, offs, cur, NN_NODES);
    fill_kernel<<<(NE_EDGES + 255) / 256, 256, 0, stream>>>(src, dst, cur, csr);

    // --- conversions (fp32 row-major -> fp16 tiled) ---
    tof16_tiled_kernel<<<(NN_NODES * D_IN / 8 + 255) / 256, 256, 0, stream>>>(
        features, fhf, NN_NODES, D_IN);
    tof16_tiled_kernel<<<(D_H0 * D_IN / 8 + 255) / 256, 256, 0, stream>>>(W0, w0f, D_H0, D_IN);
    tof16_tiled_kernel<<<(D_H1 * D_H0 / 8 + 255) / 256, 256, 0, stream>>>(W1, w1f, D_H1, D_H0);
    tof16_tiled_kernel<<<(D_C * D_H1 / 8 + 255) / 256, 256, 0, stream>>>(W2, w2f, D_C, D_H1);

    // --- MLP (zero-LDS register GEMMs over tiled operands) ---
    {   // L0: [100k,512] x [512,512]^T, relu, tiled fp16 out
        int nwg = MT * 8;
        gemm_kernel<true, 1, 64, 8, 512><<<nwg, 256, 0, stream>>>(
            fhf, w0f, b0, act1, nullptr, nullptr, NN_NODES, D_H0, nwg / 8, nwg % 8);
    }
    {   // L1: [100k,512] x [256,512]^T, relu, tiled fp16 out
        int nwg = MT * 4;
        gemm_kernel<true, 1, 64, 4, 512><<<nwg, 256, 0, stream>>>(
            act1, w1f, b1, act2, nullptr, nullptr, NN_NODES, D_H1, nwg / 8, nwg % 8);
    }
    {   // L2: [100k,256] x [64,256]^T, dual row-major fp16 out (h0h, h0s=h0*ns)
        int nwg = MT;
        gemm_kernel<false, 2, 64, 1, 256><<<nwg, 256, 0, stream>>>(
            act2, w2f, b2, h0h, h0s, nsrc, NN_NODES, D_C, nwg / 8, nwg % 8);
    }

    // --- APPNP: 10 propagation steps (8 lanes per node) ---
    const _Float16* curs = h0s;
    _Float16* bufss[2] = { hAs, hBs };
    int pb = (NN_NODES * 8 + 255) / 256;   // 3125 blocks
    for (int it = 0; it < 10; it++){
        float*    out  = (it == 9) ? (float*)d_out : nullptr;
        _Float16* outs = (it == 9) ? nullptr       : bufss[it & 1];
        propagate_kernel<<<pb, 256, 0, stream>>>(curs, h0h, out, outs, offs, deg_in, csr, nsrc, ndst);
        curs = outs;
    }
}

// Round 14
// 639.468 us; speedup vs baseline: 1.1169x; 1.1169x over previous
//
#include <hip/hip_runtime.h>
#include <hip/hip_bf16.h>

#define NN_NODES 100000
#define NE_EDGES 1000000
#define D_IN 512
#define D_H0 512
#define D_H1 256
#define D_C  64

using f32x4  = __attribute__((ext_vector_type(4))) float;
using h16x8  = __attribute__((ext_vector_type(8))) _Float16;

// async global->LDS, 16B/lane; LDS dest = wave-uniform base + lane*16
static __device__ __forceinline__ void gll16(const _Float16* g, _Float16* l){
    __builtin_amdgcn_global_load_lds(
        (const __attribute__((address_space(1))) unsigned int*)g,
        (__attribute__((address_space(3))) unsigned int*)l, 16, 0, 0);
}

// ---------------- fp32 row-major -> fp16 TILED [(R/128)][(K/32)][128x32] ----------------
__global__ __launch_bounds__(256) void tof16_tiled_kernel(
    const float* __restrict__ w, _Float16* __restrict__ o, int R, int K)
{
    int i = blockIdx.x * 256 + threadIdx.x;      // 8 elems along a row
    int n8 = R * (K >> 3);
    if (i >= n8) return;
    int kd = K >> 3;
    int r  = i / kd;
    int c0 = (i - r * kd) * 8;
    const f32x4 a = *(const f32x4*)(w + (size_t)r * K + c0);
    const f32x4 b = *(const f32x4*)(w + (size_t)r * K + c0 + 4);
    h16x8 h;
    #pragma unroll
    for (int j = 0; j < 4; j++){
        h[j]   = (_Float16)a[j];
        h[j+4] = (_Float16)b[j];
    }
    size_t off = ((size_t)(r >> 7) * (K >> 5) + (c0 >> 5)) * 4096
               + (size_t)(r & 127) * 32 + (c0 & 31);
    *(h16x8*)(o + off) = h;
}

// ---------------- GEMM: C[M,NNc] = act( A[M,K] * B[NNc,K]^T + bias ) ----------------
// r12 proven config (BN_T=64, 40 VGPR, 4 blocks/CU) + T3/T4 pipeline:
// 3-buffer LDS, stage(t+2) pre-issued 2 k-steps (~1400 cyc) before use,
// steady-state s_waitcnt vmcnt(6) (= stages t+1,t+2 in flight per wave;
// stage-t loads long landed), raw s_barrier pair per k-step -- barrier
// arrival is compute-paced, not load-drain-paced (the r12 bottleneck).
// Tiled operands (contiguous 1KB per gll), XOR chunk-swizzle (0 conflicts).
// OMODE: 1 fp16 out TILED; 2 dual row-major fp16 out (O1=v, O2=v*scale[row]).
template<bool RELU, int OMODE, int BN_T, int NBN, int KK>
__global__ __launch_bounds__(256, 4) void gemm_kernel(
    const _Float16* __restrict__ A,
    const _Float16* __restrict__ B,
    const float* __restrict__ bias,
    void* __restrict__ O1, _Float16* __restrict__ O2, const float* __restrict__ scale,
    int M, int NNc, int xq, int xr)
{
    constexpr int NTK  = KK / 32;          // k-steps
    constexpr int NF   = BN_T / 32;        // n-fragments per wave (2)
    constexpr int BBLK = BN_T / 16;        // 16-row gll blocks per B tile (4)
    constexpr int TOT  = 8 + BBLK;         // gll ops per k-step (12)
    constexpr int LPW  = TOT / 4;          // gll ops per wave per stage (3)

    __shared__ _Float16 sA[3][128 * 32];
    __shared__ _Float16 sB[3][BN_T * 32];

    const int tid  = threadIdx.x;
    const int lane = tid & 63;
    const int wv   = tid >> 6;
    const int wm   = wv >> 1;
    const int wn   = wv & 1;
    const int fr   = lane & 15;
    const int fc   = lane >> 4;

    // bijective XCD-chunk swizzle (m204)
    const int bid = blockIdx.x;
    const int xcd = bid & 7;
    const int i8  = bid >> 3;
    const int L   = ((xcd < xr) ? xcd * (xq + 1) : xr * (xq + 1) + (xcd - xr) * xq) + i8;
    const int mt  = L / NBN;
    const int bn  = L - mt * NBN;
    const int bm0 = mt * 128;
    const int bn0 = bn * BN_T;

    // B rows live in 128-row slabs: locate tile within its slab
    const int bslab = bn0 >> 7;
    const int binsl = bn0 & 127;

    // per-lane offset within a 1KB staging block (chunk XOR-swizzled source)
    const int loff = (lane >> 2) * 32 + ((lane & 3) ^ ((lane >> 3) & 3)) * 8;

    f32x4 acc[4][NF] = {};

    auto stage = [&](int b, int t){
        const _Float16* as = A + ((size_t)mt * NTK + t) * 4096;
        const _Float16* bs = B + ((size_t)bslab * NTK + t) * 4096 + binsl * 32;
        #pragma unroll
        for (int u = 0; u < LPW; u++){
            int idx = u * 4 + wv;
            if (idx < 8) gll16(as + idx * 512 + loff, sA[b] + idx * 512);
            else         gll16(bs + (idx - 8) * 512 + loff, sB[b] + (idx - 8) * 512);
        }
    };

    auto compute = [&](int b){
        h16x8 bf[NF];
        #pragma unroll
        for (int nf = 0; nf < NF; nf++){
            int r = wn * (BN_T / 2) + nf * 16 + fr;
            int c = (fc ^ ((r >> 1) & 3)) * 8;
            bf[nf] = *(const h16x8*)&sB[b][r * 32 + c];
        }
        h16x8 af[4];
        #pragma unroll
        for (int mf = 0; mf < 4; mf++){
            int r = wm * 64 + mf * 16 + fr;
            int c = (fc ^ ((r >> 1) & 3)) * 8;
            af[mf] = *(const h16x8*)&sA[b][r * 32 + c];
        }
        __builtin_amdgcn_s_setprio(1);
        #pragma unroll
        for (int mf = 0; mf < 4; mf++)
            #pragma unroll
            for (int nf = 0; nf < NF; nf++)
                acc[mf][nf] = __builtin_amdgcn_mfma_f32_16x16x32_f16(af[mf], bf[nf], acc[mf][nf], 0, 0, 0);
        __builtin_amdgcn_s_setprio(0);
    };

    // prologue: 2 stages in flight before first compute
    stage(0, 0);
    stage(1, 1);
    for (int t = 0; t < NTK; t++){
        if (t + 2 < NTK){
            stage((t + 2) % 3, t + 2);
            // stage-t loads issued 2 iters ago; keep stages t+1,t+2 in flight
            asm volatile("s_waitcnt vmcnt(6)" ::: "memory");
        } else if (t + 1 < NTK){
            asm volatile("s_waitcnt vmcnt(3)" ::: "memory");
        } else {
            asm volatile("s_waitcnt vmcnt(0)" ::: "memory");
        }
        __builtin_amdgcn_s_barrier();       // all waves' stage-t contributions done
        asm volatile("" ::: "memory");
        compute(t % 3);
        asm volatile("" ::: "memory");
        __builtin_amdgcn_s_barrier();       // compute(t) retired before buf reuse
        asm volatile("" ::: "memory");
    }

    // ---- epilogue ----
    #pragma unroll
    for (int mf = 0; mf < 4; mf++){
        #pragma unroll
        for (int nf = 0; nf < NF; nf++){
            #pragma unroll
            for (int r = 0; r < 4; r++){
                int rg = bm0 + wm * 64 + mf * 16 + fc * 4 + r;
                int cg = bn0 + wn * (BN_T / 2) + nf * 16 + fr;
                if (rg < M){
                    float v = acc[mf][nf][r] + bias[cg];
                    if constexpr (RELU) v = fmaxf(v, 0.f);
                    if constexpr (OMODE == 1){
                        size_t o = ((size_t)mt * (NNc >> 5) + (cg >> 5)) * 4096
                                 + (size_t)(rg & 127) * 32 + (cg & 31);
                        ((_Float16*)O1)[o] = (_Float16)v;
                    } else {
                        ((_Float16*)O1)[(size_t)rg * NNc + cg] = (_Float16)v;
                        O2[(size_t)rg * NNc + cg] = (_Float16)(v * scale[rg]);
                    }
                }
            }
        }
    }
}

// ---------------- graph preprocessing ----------------
__global__ void degrees_kernel(const int* __restrict__ src, const int* __restrict__ dst,
                               int* __restrict__ dout, int* __restrict__ din){
    int e = blockIdx.x * blockDim.x + threadIdx.x;
    if (e < NE_EDGES){
        atomicAdd(&dout[src[e]], 1);
        atomicAdd(&din[dst[e]], 1);
    }
}

__global__ void norm_kernel(const int* __restrict__ dout, const int* __restrict__ din,
                            float* __restrict__ ns, float* __restrict__ nd, int n){
    int i = blockIdx.x * blockDim.x + threadIdx.x;
    if (i < n){
        ns[i] = rsqrtf((float)(dout[i] > 1 ? dout[i] : 1));
        nd[i] = rsqrtf((float)(din[i]  > 1 ? din[i]  : 1));
    }
}

__global__ __launch_bounds__(256) void scan1_kernel(const int* __restrict__ din,
                                                    int* __restrict__ part,
                                                    int* __restrict__ bsum, int n){
    __shared__ int s[256];
    int i = blockIdx.x * 256 + threadIdx.x;
    int v = (i < n) ? din[i] : 0;
    s[threadIdx.x] = v;
    __syncthreads();
    for (int off = 1; off < 256; off <<= 1){
        int t = (threadIdx.x >= off) ? s[threadIdx.x - off] : 0;
        __syncthreads();
        s[threadIdx.x] += t;
        __syncthreads();
    }
    if (i < n) part[i] = s[threadIdx.x];
    if (threadIdx.x == 255) bsum[blockIdx.x] = s[255];
}

__global__ __launch_bounds__(512) void scan2_kernel(int* __restrict__ bsum, int nb){
    __shared__ int s[512];
    int v = (threadIdx.x < nb) ? bsum[threadIdx.x] : 0;
    s[threadIdx.x] = v;
    __syncthreads();
    for (int off = 1; off < 512; off <<= 1){
        int t = (threadIdx.x >= off) ? s[threadIdx.x - off] : 0;
        __syncthreads();
        s[threadIdx.x] += t;
        __syncthreads();
    }
    if (threadIdx.x < nb) bsum[threadIdx.x] = s[threadIdx.x];
}

__global__ void scan3_kernel(const int* __restrict__ part, const int* __restrict__ din,
                             const int* __restrict__ bsum, int* __restrict__ offs,
                             int* __restrict__ cur, int n){
    int i = blockIdx.x * 256 + threadIdx.x;
    if (i < n){
        int base = (blockIdx.x > 0) ? bsum[blockIdx.x - 1] : 0;
        int excl = base + part[i] - din[i];
        offs[i] = excl;
        cur[i]  = excl;
    }
}

__global__ void fill_kernel(const int* __restrict__ src, const int* __restrict__ dst,
                            int* __restrict__ cur, int* __restrict__ csr){
    int e = blockIdx.x * blockDim.x + threadIdx.x;
    if (e < NE_EDGES){
        int d = dst[e];
        int pos = atomicAdd(&cur[d], 1);
        csr[pos] = src[e];
    }
}

// ---------------- APPNP propagation: 8 lanes per node, 4-way unrolled ----------------
__global__ __launch_bounds__(256) void propagate_kernel(
    const _Float16* __restrict__ hs, const _Float16* __restrict__ h0h,
    float* __restrict__ hout, _Float16* __restrict__ houts,
    const int* __restrict__ offs, const int* __restrict__ din,
    const int* __restrict__ csr,
    const float* __restrict__ ns, const float* __restrict__ nd)
{
    int t    = blockIdx.x * 256 + threadIdx.x;
    int node = t >> 3;
    int gl   = t & 7;
    if (node >= NN_NODES) return;
    int start = offs[node];
    int deg   = din[node];
    float acc[8] = {};
    int j = 0;
    for (; j + 4 <= deg; j += 4){
        int s0 = csr[start + j];
        int s1 = csr[start + j + 1];
        int s2 = csr[start + j + 2];
        int s3 = csr[start + j + 3];
        h16x8 v0 = *(const h16x8*)(hs + (size_t)s0 * D_C + gl * 8);
        h16x8 v1 = *(const h16x8*)(hs + (size_t)s1 * D_C + gl * 8);
        h16x8 v2 = *(const h16x8*)(hs + (size_t)s2 * D_C + gl * 8);
        h16x8 v3 = *(const h16x8*)(hs + (size_t)s3 * D_C + gl * 8);
        #pragma unroll
        for (int i = 0; i < 8; i++)
            acc[i] += ((float)v0[i] + (float)v1[i]) + ((float)v2[i] + (float)v3[i]);
    }
    for (; j < deg; j++){
        int s0 = csr[start + j];
        h16x8 v0 = *(const h16x8*)(hs + (size_t)s0 * D_C + gl * 8);
        #pragma unroll
        for (int i = 0; i < 8; i++) acc[i] += (float)v0[i];
    }
    float ndv = 0.9f * nd[node];
    h16x8 h0v = *(const h16x8*)(h0h + (size_t)node * D_C + gl * 8);
    float out[8];
    #pragma unroll
    for (int i = 0; i < 8; i++) out[i] = acc[i] * ndv + 0.1f * (float)h0v[i];
    if (houts){
        float nsv = ns[node];
        h16x8 o;
        #pragma unroll
        for (int i = 0; i < 8; i++) o[i] = (_Float16)(out[i] * nsv);
        *(h16x8*)(houts + (size_t)node * D_C + gl * 8) = o;
    }
    if (hout){
        f32x4 oa, ob;
        #pragma unroll
        for (int i = 0; i < 4; i++){ oa[i] = out[i]; ob[i] = out[i + 4]; }
        *(f32x4*)(hout + (size_t)node * D_C + gl * 8)     = oa;
        *(f32x4*)(hout + (size_t)node * D_C + gl * 8 + 4) = ob;
    }
}

// ---------------- launch ----------------
extern "C" void kernel_launch(void* const* d_in, const int* in_sizes, int n_in,
                              void* d_out, int out_size, void* d_ws, size_t ws_size,
                              hipStream_t stream)
{
    const float* features = (const float*)d_in[0];
    const int*   edge     = (const int*)d_in[1];
    const float* W0 = (const float*)d_in[2];
    const float* b0 = (const float*)d_in[3];
    const float* W1 = (const float*)d_in[4];
    const float* b1 = (const float*)d_in[5];
    const float* W2 = (const float*)d_in[6];
    const float* b2 = (const float*)d_in[7];
    const int* src = edge;
    const int* dst = edge + NE_EDGES;

    char* p = (char*)d_ws;
    auto alloc = [&](size_t bytes) -> char* {
        char* r = p;
        p += (bytes + 255) & ~(size_t)255;
        return r;
    };

    const int MT = (NN_NODES + 127) / 128;              // 782 m-tiles
    const size_t FEAT_T = (size_t)MT * 16 * 4096 * 2;   // tiled fp16, K=512
    const size_t HBUFH  = (size_t)NN_NODES * D_C * 2;   // 12.8 MB fp16

    _Float16* w0f = (_Float16*)alloc((size_t)4 * 16 * 4096 * 2);  // 512 rows
    _Float16* w1f = (_Float16*)alloc((size_t)2 * 16 * 4096 * 2);  // 256 rows
    _Float16* w2f = (_Float16*)alloc((size_t)1 * 8  * 4096 * 2);  // 64 rows
    char* R1 = alloc(FEAT_T);          // fhf (tiled); later act2 (tiled)
    char* R2 = alloc(FEAT_T);          // act1 (tiled); later h0h + h0s + hAs + hBs
    int*   deg_out = (int*)alloc((size_t)NN_NODES * 4);
    int*   deg_in  = (int*)alloc((size_t)NN_NODES * 4);
    float* nsrc    = (float*)alloc((size_t)NN_NODES * 4);
    float* ndst    = (float*)alloc((size_t)NN_NODES * 4);
    int*   part    = (int*)alloc((size_t)NN_NODES * 4);
    int*   bsum    = (int*)alloc(2048);
    int*   offs    = (int*)alloc((size_t)NN_NODES * 4);
    int*   cur     = (int*)alloc((size_t)NN_NODES * 4);
    int*   csr     = (int*)alloc((size_t)NE_EDGES * 4);
    if ((size_t)(p - (char*)d_ws) > ws_size) return;

    _Float16* fhf  = (_Float16*)R1;          // dead after GEMM1
    _Float16* act2 = (_Float16*)R1;          // written by GEMM2 (tiled)
    _Float16* act1 = (_Float16*)R2;          // dead after GEMM2
    _Float16* h0h  = (_Float16*)R2;          // written by GEMM3 (row-major fp16)
    _Float16* h0s  = (_Float16*)(R2 + HBUFH);
    _Float16* hAs  = (_Float16*)(R2 + 2 * HBUFH);
    _Float16* hBs  = (_Float16*)(R2 + 3 * HBUFH);

    // --- graph preprocessing ---
    hipMemsetAsync(deg_out, 0, (size_t)NN_NODES * 4, stream);
    hipMemsetAsync(deg_in,  0, (size_t)NN_NODES * 4, stream);
    degrees_kernel<<<(NE_EDGES + 255) / 256, 256, 0, stream>>>(src, dst, deg_out, deg_in);
    norm_kernel<<<(NN_NODES + 255) / 256, 256, 0, stream>>>(deg_out, deg_in, nsrc, ndst, NN_NODES);
    int nb = (NN_NODES + 255) / 256;
    scan1_kernel<<<nb, 256, 0, stream>>>(deg_in, part, bsum, NN_NODES);
    scan2_kernel<<<1, 512, 0, stream>>>(bsum, nb);
    scan3_kernel<<<nb, 256, 0, stream>>>(part, deg_in, bsum, offs, cur, NN_NODES);
    fill_kernel<<<(NE_EDGES + 255) / 256, 256, 0, stream>>>(src, dst, cur, csr);

    // --- conversions (fp32 row-major -> fp16 tiled) ---
    tof16_tiled_kernel<<<(NN_NODES * D_IN / 8 + 255) / 256, 256, 0, stream>>>(
        features, fhf, NN_NODES, D_IN);
    tof16_tiled_kernel<<<(D_H0 * D_IN / 8 + 255) / 256, 256, 0, stream>>>(W0, w0f, D_H0, D_IN);
    tof16_tiled_kernel<<<(D_H1 * D_H0 / 8 + 255) / 256, 256, 0, stream>>>(W1, w1f, D_H1, D_H0);
    tof16_tiled_kernel<<<(D_C * D_H1 / 8 + 255) / 256, 256, 0, stream>>>(W2, w2f, D_C, D_H1);

    // --- MLP (BN_T=64, 3-buffer counted-vmcnt pipeline) ---
    {   // L0: [100k,512] x [512,512]^T, relu, tiled fp16 out
        int nwg = MT * 8;
        gemm_kernel<true, 1, 64, 8, 512><<<nwg, 256, 0, stream>>>(
            fhf, w0f, b0, act1, nullptr, nullptr, NN_NODES, D_H0, nwg / 8, nwg % 8);
    }
    {   // L1: [100k,512] x [256,512]^T, relu, tiled fp16 out
        int nwg = MT * 4;
        gemm_kernel<true, 1, 64, 4, 512><<<nwg, 256, 0, stream>>>(
            act1, w1f, b1, act2, nullptr, nullptr, NN_NODES, D_H1, nwg / 8, nwg % 8);
    }
    {   // L2: [100k,256] x [64,256]^T, dual row-major fp16 out (h0h, h0s=h0*ns)
        int nwg = MT;
        gemm_kernel<false, 2, 64, 1, 256><<<nwg, 256, 0, stream>>>(
            act2, w2f, b2, h0h, h0s, nsrc, NN_NODES, D_C, nwg / 8, nwg % 8);
    }

    // --- APPNP: 10 propagation steps (8 lanes per node) ---
    const _Float16* curs = h0s;
    _Float16* bufss[2] = { hAs, hBs };
    int pb = (NN_NODES * 8 + 255) / 256;   // 3125 blocks
    for (int it = 0; it < 10; it++){
        float*    out  = (it == 9) ? (float*)d_out : nullptr;
        _Float16* outs = (it == 9) ? nullptr       : bufss[it & 1];
        propagate_kernel<<<pb, 256, 0, stream>>>(curs, h0h, out, outs, offs, deg_in, csr, nsrc, ndst);
        curs = outs;
    }
}

// Round 15
// 609.039 us; speedup vs baseline: 1.1727x; 1.0500x over previous
//
#include <hip/hip_runtime.h>
#include <hip/hip_bf16.h>

#define NN_NODES 100000
#define NE_EDGES 1000000
#define D_IN 512
#define D_H0 512
#define D_H1 256
#define D_C  64

using f32x4  = __attribute__((ext_vector_type(4))) float;
using h16x8  = __attribute__((ext_vector_type(8))) _Float16;

// async global->LDS, 16B/lane; LDS dest = wave-uniform base + lane*16
static __device__ __forceinline__ void gll16(const _Float16* g, _Float16* l){
    __builtin_amdgcn_global_load_lds(
        (const __attribute__((address_space(1))) unsigned int*)g,
        (__attribute__((address_space(3))) unsigned int*)l, 16, 0, 0);
}

// ---------------- fp32 row-major -> fp16 TILED [(R/128)][(K/32)][128x32] ----------------
__global__ __launch_bounds__(256) void tof16_tiled_kernel(
    const float* __restrict__ w, _Float16* __restrict__ o, int R, int K)
{
    int i = blockIdx.x * 256 + threadIdx.x;      // 8 elems along a row
    int n8 = R * (K >> 3);
    if (i >= n8) return;
    int kd = K >> 3;
    int r  = i / kd;
    int c0 = (i - r * kd) * 8;
    const f32x4 a = *(const f32x4*)(w + (size_t)r * K + c0);
    const f32x4 b = *(const f32x4*)(w + (size_t)r * K + c0 + 4);
    h16x8 h;
    #pragma unroll
    for (int j = 0; j < 4; j++){
        h[j]   = (_Float16)a[j];
        h[j+4] = (_Float16)b[j];
    }
    size_t off = ((size_t)(r >> 7) * (K >> 5) + (c0 >> 5)) * 4096
               + (size_t)(r & 127) * 32 + (c0 & 31);
    *(h16x8*)(o + off) = h;
}

// ---------------- GEMM (r12 proven): C = act( A * B^T + bias ) ----------------
// 2-buffer LDS + one __syncthreads per k-step, BN_T=64, tiled operands,
// XOR chunk-swizzle both-sides. 40 VGPR -> 4 blocks/CU. Empirical best.
template<bool RELU, int OMODE, int BN_T, int NBN, int KK>
__global__ __launch_bounds__(256, 4) void gemm_kernel(
    const _Float16* __restrict__ A,
    const _Float16* __restrict__ B,
    const float* __restrict__ bias,
    void* __restrict__ O1, _Float16* __restrict__ O2, const float* __restrict__ scale,
    int M, int NNc, int xq, int xr)
{
    constexpr int NTK  = KK / 32;
    constexpr int NF   = BN_T / 32;
    constexpr int BBLK = BN_T / 16;
    constexpr int TOT  = 8 + BBLK;
    constexpr int LPW  = TOT / 4;

    __shared__ _Float16 sA[2][128 * 32];
    __shared__ _Float16 sB[2][BN_T * 32];

    const int tid  = threadIdx.x;
    const int lane = tid & 63;
    const int wv   = tid >> 6;
    const int wm   = wv >> 1;
    const int wn   = wv & 1;
    const int fr   = lane & 15;
    const int fc   = lane >> 4;

    const int bid = blockIdx.x;
    const int xcd = bid & 7;
    const int i8  = bid >> 3;
    const int L   = ((xcd < xr) ? xcd * (xq + 1) : xr * (xq + 1) + (xcd - xr) * xq) + i8;
    const int mt  = L / NBN;
    const int bn  = L - mt * NBN;
    const int bm0 = mt * 128;
    const int bn0 = bn * BN_T;

    const int bslab = bn0 >> 7;
    const int binsl = bn0 & 127;

    const int loff = (lane >> 2) * 32 + ((lane & 3) ^ ((lane >> 3) & 3)) * 8;

    f32x4 acc[4][NF] = {};

    auto stage = [&](int b, int t){
        const _Float16* as = A + ((size_t)mt * NTK + t) * 4096;
        const _Float16* bs = B + ((size_t)bslab * NTK + t) * 4096 + binsl * 32;
        #pragma unroll
        for (int u = 0; u < LPW; u++){
            int idx = u * 4 + wv;
            if (idx < 8) gll16(as + idx * 512 + loff, sA[b] + idx * 512);
            else         gll16(bs + (idx - 8) * 512 + loff, sB[b] + (idx - 8) * 512);
        }
    };

    auto compute = [&](int b){
        h16x8 bf[NF];
        #pragma unroll
        for (int nf = 0; nf < NF; nf++){
            int r = wn * (BN_T / 2) + nf * 16 + fr;
            int c = (fc ^ ((r >> 1) & 3)) * 8;
            bf[nf] = *(const h16x8*)&sB[b][r * 32 + c];
        }
        h16x8 af[4];
        #pragma unroll
        for (int mf = 0; mf < 4; mf++){
            int r = wm * 64 + mf * 16 + fr;
            int c = (fc ^ ((r >> 1) & 3)) * 8;
            af[mf] = *(const h16x8*)&sA[b][r * 32 + c];
        }
        __builtin_amdgcn_s_setprio(1);
        #pragma unroll
        for (int mf = 0; mf < 4; mf++)
            #pragma unroll
            for (int nf = 0; nf < NF; nf++)
                acc[mf][nf] = __builtin_amdgcn_mfma_f32_16x16x32_f16(af[mf], bf[nf], acc[mf][nf], 0, 0, 0);
        __builtin_amdgcn_s_setprio(0);
    };

    stage(0, 0);
    __syncthreads();
    int cur = 0;
    for (int t = 0; t < NTK; t++){
        if (t + 1 < NTK) stage(cur ^ 1, t + 1);
        compute(cur);
        __syncthreads();
        cur ^= 1;
    }

    #pragma unroll
    for (int mf = 0; mf < 4; mf++){
        #pragma unroll
        for (int nf = 0; nf < NF; nf++){
            #pragma unroll
            for (int r = 0; r < 4; r++){
                int rg = bm0 + wm * 64 + mf * 16 + fc * 4 + r;
                int cg = bn0 + wn * (BN_T / 2) + nf * 16 + fr;
                if (rg < M){
                    float v = acc[mf][nf][r] + bias[cg];
                    if constexpr (RELU) v = fmaxf(v, 0.f);
                    if constexpr (OMODE == 1){
                        size_t o = ((size_t)mt * (NNc >> 5) + (cg >> 5)) * 4096
                                 + (size_t)(rg & 127) * 32 + (cg & 31);
                        ((_Float16*)O1)[o] = (_Float16)v;
                    } else {
                        ((_Float16*)O1)[(size_t)rg * NNc + cg] = (_Float16)v;
                        O2[(size_t)rg * NNc + cg] = (_Float16)(v * scale[rg]);
                    }
                }
            }
        }
    }
}

// ---------------- FUSED GEMM2+GEMM3 ----------------
// Block = 128 rows x FULL 256 cols of act2 (so layer-3 can finish locally).
// 8 waves (512 thr), wave tile 64x64, K=512 phase-1 identical structure to
// the proven r12 loop. Epilogue: act2 (bias1+relu) -> LDS slab layout with
// XOR chunk swizzle; phase 2: h0 = act2 @ W2^T + b2 from LDS (W2 pre-staged
// at kernel start into a disjoint LDS region). Emits h0h and h0s=h0*nsrc.
// Saves the 102MB act2 HBM round-trip + the separate GEMM3 dispatch.
// LDS: stage 2x24KB = 48KB (reused by act2 64KB after k-loop) + W2 32KB = 96KB.
__global__ __launch_bounds__(512, 2) void gemm23_kernel(
    const _Float16* __restrict__ A,     // act1 tiled, K=512
    const _Float16* __restrict__ B1,    // w1f tiled (2 slabs), K=512
    const _Float16* __restrict__ B2,    // w2f tiled (slab rows 0-63), K=256
    const float* __restrict__ bias1,
    const float* __restrict__ bias2,
    _Float16* __restrict__ h0h, _Float16* __restrict__ h0s,
    const float* __restrict__ nsrc,
    int M, int xq, int xr)
{
    constexpr int NTK = 16;             // K = 512
    __shared__ _Float16 smem[49152];    // 96 KB

    const int tid  = threadIdx.x;
    const int lane = tid & 63;
    const int wv   = tid >> 6;          // 0..7
    const int wm   = wv >> 2;           // 0..1
    const int wn   = wv & 3;            // 0..3
    const int fr   = lane & 15;
    const int fc   = lane >> 4;

    const int bid = blockIdx.x;
    const int xcd = bid & 7;
    const int i8  = bid >> 3;
    const int mt  = ((xcd < xr) ? xcd * (xq + 1) : xr * (xq + 1) + (xcd - xr) * xq) + i8;
    const int bm0 = mt * 128;

    const int loff = (lane >> 2) * 32 + ((lane & 3) ^ ((lane >> 3) & 3)) * 8;

    _Float16* sW2 = smem + 32768;       // 8 slabs x [64][32] = 16K elems (32KB)

    // stage W2 once (region disjoint from k-loop staging; drained by 1st barrier)
    #pragma unroll
    for (int u = 0; u < 4; u++){
        int idx = u * 8 + wv;           // 0..31
        int k = idx >> 2, rb = idx & 3;
        gll16(B2 + (size_t)k * 4096 + rb * 512 + loff, sW2 + k * 2048 + rb * 512);
    }

    auto sA = [&](int b){ return smem + b * 12288; };
    auto sB = [&](int b){ return smem + b * 12288 + 4096; };

    auto stage = [&](int b, int t){
        #pragma unroll
        for (int u = 0; u < 3; u++){
            int idx = u * 8 + wv;       // 0..23
            if (idx < 8){
                gll16(A + ((size_t)mt * NTK + t) * 4096 + idx * 512 + loff,
                      sA(b) + idx * 512);
            } else {
                int rb = idx - 8;       // 0..15 (256 B rows = 2 slabs)
                gll16(B1 + ((size_t)(rb >> 3) * NTK + t) * 4096 + (rb & 7) * 512 + loff,
                      sB(b) + rb * 512);
            }
        }
    };

    f32x4 acc[4][4] = {};

    auto compute = [&](int b){
        h16x8 bf[4];
        #pragma unroll
        for (int nf = 0; nf < 4; nf++){
            int r = wn * 64 + nf * 16 + fr;
            int c = (fc ^ ((r >> 1) & 3)) * 8;
            bf[nf] = *(const h16x8*)&sB(b)[r * 32 + c];
        }
        h16x8 af[4];
        #pragma unroll
        for (int mf = 0; mf < 4; mf++){
            int r = wm * 64 + mf * 16 + fr;
            int c = (fc ^ ((r >> 1) & 3)) * 8;
            af[mf] = *(const h16x8*)&sA(b)[r * 32 + c];
        }
        __builtin_amdgcn_s_setprio(1);
        #pragma unroll
        for (int mf = 0; mf < 4; mf++)
            #pragma unroll
            for (int nf = 0; nf < 4; nf++)
                acc[mf][nf] = __builtin_amdgcn_mfma_f32_16x16x32_f16(af[mf], bf[nf], acc[mf][nf], 0, 0, 0);
        __builtin_amdgcn_s_setprio(0);
    };

    stage(0, 0);
    __syncthreads();
    int cur = 0;
    for (int t = 0; t < NTK; t++){
        if (t + 1 < NTK) stage(cur ^ 1, t + 1);
        compute(cur);
        __syncthreads();
        cur ^= 1;
    }
    // all staging reads retired -> smem[0..32768) reusable for act2

    // act2 = relu(acc + b1) -> LDS slab layout [8][128][32] with XOR chunk swz
    #pragma unroll
    for (int mf = 0; mf < 4; mf++){
        #pragma unroll
        for (int nf = 0; nf < 4; nf++){
            #pragma unroll
            for (int r = 0; r < 4; r++){
                int row = wm * 64 + mf * 16 + fc * 4 + r;
                int col = wn * 64 + nf * 16 + fr;
                float v = fmaxf(acc[mf][nf][r] + bias1[col], 0.f);
                int ci = col & 31;
                int sw = ((ci >> 3) ^ ((row >> 1) & 3)) * 8 + (ci & 7);
                smem[(col >> 5) * 4096 + row * 32 + sw] = (_Float16)v;
            }
        }
    }
    __syncthreads();

    // phase 2: h0 = act2 @ W2^T + b2. Wave wv owns rows wv*16..+16, all 64 cols.
    f32x4 acc2[4] = {};
    #pragma unroll
    for (int kk = 0; kk < 8; kk++){
        int ar = wv * 16 + fr;
        int ac = (fc ^ ((ar >> 1) & 3)) * 8;
        h16x8 af = *(const h16x8*)&smem[kk * 4096 + ar * 32 + ac];
        #pragma unroll
        for (int nf = 0; nf < 4; nf++){
            int br = nf * 16 + fr;
            int bc = (fc ^ ((br >> 1) & 3)) * 8;
            h16x8 bf = *(const h16x8*)&sW2[kk * 2048 + br * 32 + bc];
            acc2[nf] = __builtin_amdgcn_mfma_f32_16x16x32_f16(af, bf, acc2[nf], 0, 0, 0);
        }
    }
    #pragma unroll
    for (int nf = 0; nf < 4; nf++){
        #pragma unroll
        for (int r = 0; r < 4; r++){
            int rg = bm0 + wv * 16 + fc * 4 + r;
            int cg = nf * 16 + fr;
            if (rg < M){
                float v = acc2[nf][r] + bias2[cg];
                h0h[(size_t)rg * D_C + cg] = (_Float16)v;
                h0s[(size_t)rg * D_C + cg] = (_Float16)(v * nsrc[rg]);
            }
        }
    }
}

// ---------------- graph preprocessing ----------------
__global__ void degrees_kernel(const int* __restrict__ src, const int* __restrict__ dst,
                               int* __restrict__ dout, int* __restrict__ din){
    int e = blockIdx.x * blockDim.x + threadIdx.x;
    if (e < NE_EDGES){
        atomicAdd(&dout[src[e]], 1);
        atomicAdd(&din[dst[e]], 1);
    }
}

__global__ void norm_kernel(const int* __restrict__ dout, const int* __restrict__ din,
                            float* __restrict__ ns, float* __restrict__ nd, int n){
    int i = blockIdx.x * blockDim.x + threadIdx.x;
    if (i < n){
        ns[i] = rsqrtf((float)(dout[i] > 1 ? dout[i] : 1));
        nd[i] = rsqrtf((float)(din[i]  > 1 ? din[i]  : 1));
    }
}

__global__ __launch_bounds__(256) void scan1_kernel(const int* __restrict__ din,
                                                    int* __restrict__ part,
                                                    int* __restrict__ bsum, int n){
    __shared__ int s[256];
    int i = blockIdx.x * 256 + threadIdx.x;
    int v = (i < n) ? din[i] : 0;
    s[threadIdx.x] = v;
    __syncthreads();
    for (int off = 1; off < 256; off <<= 1){
        int t = (threadIdx.x >= off) ? s[threadIdx.x - off] : 0;
        __syncthreads();
        s[threadIdx.x] += t;
        __syncthreads();
    }
    if (i < n) part[i] = s[threadIdx.x];
    if (threadIdx.x == 255) bsum[blockIdx.x] = s[255];
}

__global__ __launch_bounds__(512) void scan2_kernel(int* __restrict__ bsum, int nb){
    __shared__ int s[512];
    int v = (threadIdx.x < nb) ? bsum[threadIdx.x] : 0;
    s[threadIdx.x] = v;
    __syncthreads();
    for (int off = 1; off < 512; off <<= 1){
        int t = (threadIdx.x >= off) ? s[threadIdx.x - off] : 0;
        __syncthreads();
        s[threadIdx.x] += t;
        __syncthreads();
    }
    if (threadIdx.x < nb) bsum[threadIdx.x] = s[threadIdx.x];
}

__global__ void scan3_kernel(const int* __restrict__ part, const int* __restrict__ din,
                             const int* __restrict__ bsum, int* __restrict__ offs,
                             int* __restrict__ cur, int n){
    int i = blockIdx.x * 256 + threadIdx.x;
    if (i < n){
        int base = (blockIdx.x > 0) ? bsum[blockIdx.x - 1] : 0;
        int excl = base + part[i] - din[i];
        offs[i] = excl;
        cur[i]  = excl;
    }
}

__global__ void fill_kernel(const int* __restrict__ src, const int* __restrict__ dst,
                            int* __restrict__ cur, int* __restrict__ csr){
    int e = blockIdx.x * blockDim.x + threadIdx.x;
    if (e < NE_EDGES){
        int d = dst[e];
        int pos = atomicAdd(&cur[d], 1);
        csr[pos] = src[e];
    }
}

// ---------------- APPNP propagation: 8 lanes per node, 4-way unrolled ----------------
__global__ __launch_bounds__(256) void propagate_kernel(
    const _Float16* __restrict__ hs, const _Float16* __restrict__ h0h,
    float* __restrict__ hout, _Float16* __restrict__ houts,
    const int* __restrict__ offs, const int* __restrict__ din,
    const int* __restrict__ csr,
    const float* __restrict__ ns, const float* __restrict__ nd)
{
    int t    = blockIdx.x * 256 + threadIdx.x;
    int node = t >> 3;
    int gl   = t & 7;
    if (node >= NN_NODES) return;
    int start = offs[node];
    int deg   = din[node];
    float acc[8] = {};
    int j = 0;
    for (; j + 4 <= deg; j += 4){
        int s0 = csr[start + j];
        int s1 = csr[start + j + 1];
        int s2 = csr[start + j + 2];
        int s3 = csr[start + j + 3];
        h16x8 v0 = *(const h16x8*)(hs + (size_t)s0 * D_C + gl * 8);
        h16x8 v1 = *(const h16x8*)(hs + (size_t)s1 * D_C + gl * 8);
        h16x8 v2 = *(const h16x8*)(hs + (size_t)s2 * D_C + gl * 8);
        h16x8 v3 = *(const h16x8*)(hs + (size_t)s3 * D_C + gl * 8);
        #pragma unroll
        for (int i = 0; i < 8; i++)
            acc[i] += ((float)v0[i] + (float)v1[i]) + ((float)v2[i] + (float)v3[i]);
    }
    for (; j < deg; j++){
        int s0 = csr[start + j];
        h16x8 v0 = *(const h16x8*)(hs + (size_t)s0 * D_C + gl * 8);
        #pragma unroll
        for (int i = 0; i < 8; i++) acc[i] += (float)v0[i];
    }
    float ndv = 0.9f * nd[node];
    h16x8 h0v = *(const h16x8*)(h0h + (size_t)node * D_C + gl * 8);
    float out[8];
    #pragma unroll
    for (int i = 0; i < 8; i++) out[i] = acc[i] * ndv + 0.1f * (float)h0v[i];
    if (houts){
        float nsv = ns[node];
        h16x8 o;
        #pragma unroll
        for (int i = 0; i < 8; i++) o[i] = (_Float16)(out[i] * nsv);
        *(h16x8*)(houts + (size_t)node * D_C + gl * 8) = o;
    }
    if (hout){
        f32x4 oa, ob;
        #pragma unroll
        for (int i = 0; i < 4; i++){ oa[i] = out[i]; ob[i] = out[i + 4]; }
        *(f32x4*)(hout + (size_t)node * D_C + gl * 8)     = oa;
        *(f32x4*)(hout + (size_t)node * D_C + gl * 8 + 4) = ob;
    }
}

// ---------------- launch ----------------
extern "C" void kernel_launch(void* const* d_in, const int* in_sizes, int n_in,
                              void* d_out, int out_size, void* d_ws, size_t ws_size,
                              hipStream_t stream)
{
    const float* features = (const float*)d_in[0];
    const int*   edge     = (const int*)d_in[1];
    const float* W0 = (const float*)d_in[2];
    const float* b0 = (const float*)d_in[3];
    const float* W1 = (const float*)d_in[4];
    const float* b1 = (const float*)d_in[5];
    const float* W2 = (const float*)d_in[6];
    const float* b2 = (const float*)d_in[7];
    const int* src = edge;
    const int* dst = edge + NE_EDGES;

    char* p = (char*)d_ws;
    auto alloc = [&](size_t bytes) -> char* {
        char* r = p;
        p += (bytes + 255) & ~(size_t)255;
        return r;
    };

    const int MT = (NN_NODES + 127) / 128;              // 782 m-tiles
    const size_t FEAT_T = (size_t)MT * 16 * 4096 * 2;   // tiled fp16, K=512
    const size_t HBUFH  = (size_t)NN_NODES * D_C * 2;   // 12.8 MB fp16

    _Float16* w0f = (_Float16*)alloc((size_t)4 * 16 * 4096 * 2);  // 512 rows
    _Float16* w1f = (_Float16*)alloc((size_t)2 * 16 * 4096 * 2);  // 256 rows
    _Float16* w2f = (_Float16*)alloc((size_t)1 * 8  * 4096 * 2);  // 64 rows
    char* R1 = alloc(FEAT_T);          // fhf (tiled); later h0h/h0s/hAs/hBs
    char* R2 = alloc(FEAT_T);          // act1 (tiled)
    int*   deg_out = (int*)alloc((size_t)NN_NODES * 4);
    int*   deg_in  = (int*)alloc((size_t)NN_NODES * 4);
    float* nsrc    = (float*)alloc((size_t)NN_NODES * 4);
    float* ndst    = (float*)alloc((size_t)NN_NODES * 4);
    int*   part    = (int*)alloc((size_t)NN_NODES * 4);
    int*   bsum    = (int*)alloc(2048);
    int*   offs    = (int*)alloc((size_t)NN_NODES * 4);
    int*   cur     = (int*)alloc((size_t)NN_NODES * 4);
    int*   csr     = (int*)alloc((size_t)NE_EDGES * 4);
    if ((size_t)(p - (char*)d_ws) > ws_size) return;

    _Float16* fhf  = (_Float16*)R1;          // dead after GEMM1
    _Float16* act1 = (_Float16*)R2;          // input to fused GEMM23
    _Float16* h0h  = (_Float16*)R1;          // fused outputs overwrite dead fhf
    _Float16* h0s  = (_Float16*)(R1 + HBUFH);
    _Float16* hAs  = (_Float16*)(R1 + 2 * HBUFH);
    _Float16* hBs  = (_Float16*)(R1 + 3 * HBUFH);

    // --- graph preprocessing ---
    hipMemsetAsync(deg_out, 0, (size_t)NN_NODES * 4, stream);
    hipMemsetAsync(deg_in,  0, (size_t)NN_NODES * 4, stream);
    degrees_kernel<<<(NE_EDGES + 255) / 256, 256, 0, stream>>>(src, dst, deg_out, deg_in);
    norm_kernel<<<(NN_NODES + 255) / 256, 256, 0, stream>>>(deg_out, deg_in, nsrc, ndst, NN_NODES);
    int nb = (NN_NODES + 255) / 256;
    scan1_kernel<<<nb, 256, 0, stream>>>(deg_in, part, bsum, NN_NODES);
    scan2_kernel<<<1, 512, 0, stream>>>(bsum, nb);
    scan3_kernel<<<nb, 256, 0, stream>>>(part, deg_in, bsum, offs, cur, NN_NODES);
    fill_kernel<<<(NE_EDGES + 255) / 256, 256, 0, stream>>>(src, dst, cur, csr);

    // --- conversions (fp32 row-major -> fp16 tiled) ---
    tof16_tiled_kernel<<<(NN_NODES * D_IN / 8 + 255) / 256, 256, 0, stream>>>(
        features, fhf, NN_NODES, D_IN);
    tof16_tiled_kernel<<<(D_H0 * D_IN / 8 + 255) / 256, 256, 0, stream>>>(W0, w0f, D_H0, D_IN);
    tof16_tiled_kernel<<<(D_H1 * D_H0 / 8 + 255) / 256, 256, 0, stream>>>(W1, w1f, D_H1, D_H0);
    tof16_tiled_kernel<<<(D_C * D_H1 / 8 + 255) / 256, 256, 0, stream>>>(W2, w2f, D_C, D_H1);

    // --- MLP ---
    {   // L0: [100k,512] x [512,512]^T, relu, tiled fp16 out (r12 proven GEMM)
        int nwg = MT * 8;
        gemm_kernel<true, 1, 64, 8, 512><<<nwg, 256, 0, stream>>>(
            fhf, w0f, b0, act1, nullptr, nullptr, NN_NODES, D_H0, nwg / 8, nwg % 8);
    }
    {   // L1+L2 fused: act1 -> h0h (fp16) + h0s = h0*nsrc (fp16)
        int nwg = MT;
        gemm23_kernel<<<nwg, 512, 0, stream>>>(
            act1, w1f, w2f, b1, b2, h0h, h0s, nsrc, NN_NODES, nwg / 8, nwg % 8);
    }

    // --- APPNP: 10 propagation steps (8 lanes per node) ---
    const _Float16* curs = h0s;
    _Float16* bufss[2] = { hAs, hBs };
    int pb = (NN_NODES * 8 + 255) / 256;   // 3125 blocks
    for (int it = 0; it < 10; it++){
        float*    out  = (it == 9) ? (float*)d_out : nullptr;
        _Float16* outs = (it == 9) ? nullptr       : bufss[it & 1];
        propagate_kernel<<<pb, 256, 0, stream>>>(curs, h0h, out, outs, offs, deg_in, csr, nsrc, ndst);
        curs = outs;
    }
}